// Round 17
// baseline (115.457 us; speedup 1.0000x reference)
//
#include <hip/hip_runtime.h>
#include <stdint.h>

#define BS 2048   // B*S
#define E_ 512
#define NH 8
#define HD 64
#define TMAX 20

typedef unsigned long long u64;

using bf8   = __attribute__((ext_vector_type(8))) short;          // 8 bf16
using f4a   = __attribute__((ext_vector_type(4))) float;          // 4 f32 acc
using u16x8 = __attribute__((ext_vector_type(8))) unsigned short;

// ---------------------------------------------------------------------------
// f32 <-> bf16 split helpers (RNE)
// ---------------------------------------------------------------------------
__device__ __forceinline__ unsigned short f2bf(float f) {
    unsigned u = __float_as_uint(f);
    return (unsigned short)((u + 0x7FFFu + ((u >> 16) & 1u)) >> 16);
}
__device__ __forceinline__ float bf2f(unsigned short h) {
    return __uint_as_float(((unsigned)h) << 16);
}
__device__ __forceinline__ void split1(float x, unsigned short& h, unsigned short& l) {
    h = f2bf(x);
    l = f2bf(x - bf2f(h));
}

__device__ __forceinline__ void load_lds16(const void* g, void* l) {
    __builtin_amdgcn_global_load_lds(
        (const __attribute__((address_space(1))) void*)g,
        (__attribute__((address_space(3))) void*)l, 16, 0, 0);
}

// ---------------------------------------------------------------------------
// split x: f32 [n] -> hi/lo bf16. n = BS*E_ = 1M, grid 1024x256 (float4)
// ---------------------------------------------------------------------------
__global__ __launch_bounds__(256) void xsplit_kernel(const float* __restrict__ src,
    unsigned short* __restrict__ hi, unsigned short* __restrict__ lo)
{
    int i = blockIdx.x * 256 + threadIdx.x;
    float4 v = ((const float4*)src)[i];
    ushort4 h, l;
    split1(v.x, h.x, l.x);
    split1(v.y, h.y, l.y);
    split1(v.z, h.z, l.z);
    split1(v.w, h.w, l.w);
    ((ushort4*)hi)[i] = h;
    ((ushort4*)lo)[i] = l;
}

// ---------------------------------------------------------------------------
// transpose + split W: W[k][n] f32 -> Wt_hi/lo[n][k] bf16. grid (8,8,4) 256thr
// ---------------------------------------------------------------------------
__global__ __launch_bounds__(256) void wsplit_kernel(
    const float* __restrict__ Wq, const float* __restrict__ Wk,
    const float* __restrict__ Wv, const float* __restrict__ Wo,
    unsigned short* __restrict__ qkv_hi, unsigned short* __restrict__ qkv_lo,
    unsigned short* __restrict__ o_hi, unsigned short* __restrict__ o_lo)
{
    __shared__ float t[64][65];
    int z = blockIdx.z;
    const float* W = (z == 0) ? Wq : (z == 1) ? Wk : (z == 2) ? Wv : Wo;
    unsigned short* dhi = (z < 3) ? qkv_hi + (size_t)z * 512 * 512 : o_hi;
    unsigned short* dlo = (z < 3) ? qkv_lo + (size_t)z * 512 * 512 : o_lo;
    int k0 = blockIdx.y * 64, n0 = blockIdx.x * 64;
    int tid = threadIdx.x;
    int r = tid >> 4, c4 = (tid & 15) * 4;
#pragma unroll
    for (int j = 0; j < 4; ++j) {
        int row = r + j * 16;
        float4 v = *(const float4*)&W[(size_t)(k0 + row) * 512 + n0 + c4];
        t[row][c4 + 0] = v.x; t[row][c4 + 1] = v.y;
        t[row][c4 + 2] = v.z; t[row][c4 + 3] = v.w;
    }
    __syncthreads();
#pragma unroll
    for (int j = 0; j < 4; ++j) {
        int n = r + j * 16;
        ushort4 h, l;
        split1(t[c4 + 0][n], h.x, l.x);
        split1(t[c4 + 1][n], h.y, l.y);
        split1(t[c4 + 2][n], h.z, l.z);
        split1(t[c4 + 3][n], h.w, l.w);
        *(ushort4*)&dhi[(size_t)(n0 + n) * 512 + k0 + c4] = h;
        *(ushort4*)&dlo[(size_t)(n0 + n) * 512 + k0 + c4] = l;
    }
}

// ---------------------------------------------------------------------------
// LDS-staged split-bf16 MFMA GEMM (3-term), 128x128 tile, BK=32, 2-PHASE
// double-buffered. 4 waves x 64x64 quadrants, acc[4][4]. Per wave per K-step:
// 16 ds_read_b128 -> 48 MFMA (3:1 FLOP:LDS ratio, 2x the 64-tile version).
// LDS = 2ph x 4 bufs x [128][32] u16 = 64 KB. Chunk-XOR swizzle both sides.
// Per-element accumulation order identical to previous rounds (hh,hl,lh at
// each ascending k0) -> bitwise-identical output.
// grid (4 n, 16 m, z). 192 blocks (qkv) -> ~1 block/CU, single round.
// ---------------------------------------------------------------------------
__global__ __launch_bounds__(256) void gemm_lds_kernel(
    const unsigned short* __restrict__ Ag_hi, const unsigned short* __restrict__ Ag_lo,
    const unsigned short* __restrict__ Bg_hi, const unsigned short* __restrict__ Bg_lo,
    float* __restrict__ Cbase, const float* __restrict__ bias,
    int zstride_b, int zstride_c)
{
    __shared__ __align__(16) unsigned short lds[2][4][4096];   // 64 KB

    int z = blockIdx.z;
    const unsigned short* bhg = Bg_hi + (size_t)z * zstride_b;
    const unsigned short* blg = Bg_lo + (size_t)z * zstride_b;
    float* C = Cbase + (size_t)z * zstride_c;

    int tid = threadIdx.x;
    int w = tid >> 6, lane = tid & 63;
    int m0 = blockIdx.y * 128, n0 = blockIdx.x * 128;
    int mq = (w >> 1) * 64, nq = (w & 1) * 64;
    int fr = lane & 15, g8 = lane >> 4;

    // staging: 512 chunks (16B) per buf; thread does chunks tid and tid+256.
    // chunk c: row = c>>2, src col-chunk = (c&3)^(row&3)  (XOR involution)
    int c0 = tid, c1 = tid + 256;
    int sr0 = c0 >> 2, sc0 = (c0 & 3) ^ (sr0 & 3);
    int sr1 = c1 >> 2, sc1 = (c1 & 3) ^ (sr1 & 3);
    unsigned lb0 = (unsigned)c0 * 8;   // u16 offset (wave-uniform base + lane*8)
    unsigned lb1 = (unsigned)c1 * 8;

    f4a acc[4][4];
#pragma unroll
    for (int f = 0; f < 4; ++f)
#pragma unroll
        for (int g = 0; g < 4; ++g) acc[f][g] = (f4a){0.f, 0.f, 0.f, 0.f};

#define STAGE(ph, k0)                                                         \
    {                                                                         \
        size_t ga0 = (size_t)(m0 + sr0) * 512 + (k0) + sc0 * 8;               \
        size_t ga1 = (size_t)(m0 + sr1) * 512 + (k0) + sc1 * 8;               \
        size_t gb0 = (size_t)(n0 + sr0) * 512 + (k0) + sc0 * 8;               \
        size_t gb1 = (size_t)(n0 + sr1) * 512 + (k0) + sc1 * 8;               \
        load_lds16(Ag_hi + ga0, &lds[ph][0][lb0]);                            \
        load_lds16(Ag_hi + ga1, &lds[ph][0][lb1]);                            \
        load_lds16(Ag_lo + ga0, &lds[ph][1][lb0]);                            \
        load_lds16(Ag_lo + ga1, &lds[ph][1][lb1]);                            \
        load_lds16(bhg + gb0, &lds[ph][2][lb0]);                              \
        load_lds16(bhg + gb1, &lds[ph][2][lb1]);                              \
        load_lds16(blg + gb0, &lds[ph][3][lb0]);                              \
        load_lds16(blg + gb1, &lds[ph][3][lb1]);                              \
    }

#define FRAG(ph, buf, row) (*(const bf8*)&lds[ph][buf][(row) * 32 + (((g8) ^ ((row) & 3)) << 3)])

    STAGE(0, 0);
    __syncthreads();
    int ph = 0;
#pragma unroll 1
    for (int k0 = 0; k0 < 512; k0 += 32) {
        if (k0 + 32 < 512) STAGE(ph ^ 1, k0 + 32);
        bf8 ah[4], al[4], bhf[4], blf[4];
#pragma unroll
        for (int f = 0; f < 4; ++f) {
            int row = mq + f * 16 + fr;
            ah[f] = FRAG(ph, 0, row);
            al[f] = FRAG(ph, 1, row);
        }
#pragma unroll
        for (int g = 0; g < 4; ++g) {
            int row = nq + g * 16 + fr;
            bhf[g] = FRAG(ph, 2, row);
            blf[g] = FRAG(ph, 3, row);
        }
#pragma unroll
        for (int f = 0; f < 4; ++f)
#pragma unroll
            for (int g = 0; g < 4; ++g) {
                acc[f][g] = __builtin_amdgcn_mfma_f32_16x16x32_bf16(ah[f], bhf[g], acc[f][g], 0, 0, 0);
                acc[f][g] = __builtin_amdgcn_mfma_f32_16x16x32_bf16(ah[f], blf[g], acc[f][g], 0, 0, 0);
                acc[f][g] = __builtin_amdgcn_mfma_f32_16x16x32_bf16(al[f], bhf[g], acc[f][g], 0, 0, 0);
            }
        __syncthreads();
        ph ^= 1;
    }
#undef STAGE
#undef FRAG

#pragma unroll
    for (int g = 0; g < 4; ++g) {
        int col = n0 + nq + g * 16 + fr;
        float bv = bias ? bias[col] : 0.f;
#pragma unroll
        for (int f = 0; f < 4; ++f) {
            int row0 = m0 + mq + f * 16 + g8 * 4;
#pragma unroll
            for (int r = 0; r < 4; ++r)
                C[(size_t)(row0 + r) * 512 + col] = acc[f][g][r] + bv;
        }
    }
}

// ---------------------------------------------------------------------------
// Gate/complexity MLPs -> T_i. 2 tokens per 256-thread block, 1024 blocks.
// ---------------------------------------------------------------------------
__global__ __launch_bounds__(256) void mlp_gate_kernel(const float* __restrict__ x,
    const float* __restrict__ g1, const float* __restrict__ gb1,
    const float* __restrict__ g2, const float* __restrict__ gb2,
    const float* __restrict__ g3, const float* __restrict__ gb3,
    const float* __restrict__ c1, const float* __restrict__ cb1,
    const float* __restrict__ c2, const float* __restrict__ cb2,
    int* __restrict__ Ti)
{
    __shared__ __align__(16) float xsh[2][512];
    __shared__ float p1[2][4][64];
    __shared__ float h1sh[2][64];
    __shared__ float p2[2][4][32];
    __shared__ float gsh[2];
    int tid = threadIdx.x;
    int tok0 = blockIdx.x * 2;

    ((float4*)&xsh[0][0])[tid] = ((const float4*)&x[(size_t)tok0 * 512])[tid];
    __syncthreads();

    {
        int l = tid & 63, ec = tid >> 6;
        float a0 = 0.f, a1 = 0.f;
        int e0 = ec * 128;
#pragma unroll 8
        for (int t = 0; t < 128; ++t) {
            int e = e0 + t;
            float w = g1[e * 64 + l];
            a0 = fmaf(xsh[0][e], w, a0);
            a1 = fmaf(xsh[1][e], w, a1);
        }
        p1[0][ec][l] = a0;
        p1[1][ec][l] = a1;
    }
    __syncthreads();
    if (tid < 128) {
        int tok = tid >> 6, l = tid & 63;
        float h = p1[tok][0][l] + p1[tok][1][l] + p1[tok][2][l] + p1[tok][3][l] + gb1[l];
        h1sh[tok][l] = fmaxf(h, 0.f);
    }
    __syncthreads();
    {
        int m = tid & 31, g = tid >> 5, tok = g & 1, lc = g >> 1;
        float a = 0.f;
#pragma unroll
        for (int t = 0; t < 16; ++t) {
            int l = lc * 16 + t;
            a = fmaf(h1sh[tok][l], g2[l * 32 + m], a);
        }
        p2[tok][lc][m] = a;
    }
    __syncthreads();
    if (tid < 64) {
        int tok = tid >> 5, m = tid & 31;
        float h = p2[tok][0][m] + p2[tok][1][m] + p2[tok][2][m] + p2[tok][3][m] + gb2[m];
        h = fmaxf(h, 0.f);
        float v = h * g3[m];
#pragma unroll
        for (int o = 1; o < 32; o <<= 1) v += __shfl_xor(v, o);
        if (m == 0) gsh[tok] = 1.f / (1.f + expf(-(v + gb3[0])));
    }
    __syncthreads();
    {
        int m = tid & 31, g = tid >> 5, tok = g & 1, ec = g >> 1;
        float a = 0.f;
        int e0 = ec * 128;
#pragma unroll 8
        for (int t = 0; t < 128; ++t) {
            int e = e0 + t;
            a = fmaf(xsh[tok][e], c1[e * 32 + m], a);
        }
        p2[tok][ec][m] = a;
    }
    __syncthreads();
    if (tid < 64) {
        int tok = tid >> 5, m = tid & 31;
        float h = p2[tok][0][m] + p2[tok][1][m] + p2[tok][2][m] + p2[tok][3][m] + cb1[m];
        h = fmaxf(h, 0.f);
        float v = h * c2[m];
#pragma unroll
        for (int o = 1; o < 32; o <<= 1) v += __shfl_xor(v, o);
        if (m == 0) {
            float comp = 1.f / (1.f + expf(-(v + cb2[0])));
            float comb = 0.7f * gsh[tok] + 0.3f * comp;
            int t = (int)ceilf(comb * 20.f);
            t = t < 1 ? 1 : (t > 20 ? 20 : t);
            Ti[tok0 + tok] = t;
        }
    }
}

// ---------------------------------------------------------------------------
// LIF + window mask. One wave per (token, head). lane = channel within head.
// mode 0 (q): qpack[bh*512+i][t]  mode 1 (k): kpackT[bh][t][j]
// mode 2 (v): spike count as exact bf16 integer.
// ---------------------------------------------------------------------------
__global__ __launch_bounds__(256) void lif_kernel(const float* __restrict__ q,
    const float* __restrict__ k, const float* __restrict__ v,
    const int* __restrict__ Ti,
    const float* __restrict__ alphap, const float* __restrict__ betap,
    u64* __restrict__ qpack, u64* __restrict__ kpackT,
    unsigned short* __restrict__ vcnt_bf16)
{
    int mode = blockIdx.y;
    const float* src = (mode == 0) ? q : (mode == 1) ? k : v;
    int w = blockIdx.x * 4 + (threadIdx.x >> 6);   // 0..16383
    int lane = threadIdx.x & 63;
    int token = w >> 3;
    int h = w & 7;
    float xin = src[(size_t)token * 512 + h * 64 + lane];
    int T = Ti[token];
    float alpha = alphap[0], beta = betap[0];
    float vm = 0.f, isyn = 0.f;
    u64 myword = 0ull;
    int cnt = 0;
#pragma unroll
    for (int t = 0; t < TMAX; ++t) {
        isyn = alpha * isyn + xin;
        vm = beta * vm + isyn;
        bool sp = vm >= 1.0f;
        if (sp) vm = 0.f;
        bool msk = sp && (t < T);
        if (mode < 2) {
            u64 word = __ballot(msk ? 1 : 0);
            if (lane == t) myword = word;
        } else {
            cnt += msk ? 1 : 0;
        }
    }
    int b = token >> 9, i = token & 511;
    size_t bh = (size_t)(b * 8 + h);
    if (mode == 0) { if (lane < TMAX) qpack[(bh * 512 + i) * TMAX + lane] = myword; }
    else if (mode == 1) { if (lane < TMAX) kpackT[(bh * TMAX + lane) * 512 + i] = myword; }
    else { vcnt_bf16[(bh * 512 + i) * 64 + lane] = f2bf((float)cnt); }  // exact
}

// ---------------------------------------------------------------------------
// transpose vcnt: [bh][j][d] u16 -> vT[bh][d][j] u16. grid (8 jchunks, 32 bh).
// ---------------------------------------------------------------------------
__global__ __launch_bounds__(256) void vtrans_kernel(
    const unsigned short* __restrict__ vin, unsigned short* __restrict__ vout)
{
    __shared__ unsigned short t[64][80];   // pad 80: 16B-aligned rows
    int bh = blockIdx.y, j0 = blockIdx.x * 64;
    int tid = threadIdx.x;
    {
        int jl = tid >> 2, dc = (tid & 3) * 16;
        const unsigned short* src = vin + ((size_t)bh * 512 + j0 + jl) * 64 + dc;
        u16x8 a = *(const u16x8*)src;
        u16x8 b = *(const u16x8*)(src + 8);
#pragma unroll
        for (int k = 0; k < 8; ++k) t[dc + k][jl] = a[k];
#pragma unroll
        for (int k = 0; k < 8; ++k) t[dc + 8 + k][jl] = b[k];
    }
    __syncthreads();
    {
        int dl = tid >> 2, jc = (tid & 3) * 16;
        u16x8 o0 = *(const u16x8*)&t[dl][jc];
        u16x8 o1 = *(const u16x8*)&t[dl][jc + 8];
        unsigned short* dst = vout + ((size_t)bh * 64 + dl) * 512 + j0 + jc;
        *(u16x8*)dst = o0;
        *(u16x8*)(dst + 8) = o1;
    }
}

// ---------------------------------------------------------------------------
// attn: 256 threads (4 waves), 2048 blocks, LDS 18688 B -> 8 blocks/CU.
// (unchanged from round 15)
// ---------------------------------------------------------------------------
__global__ __launch_bounds__(256, 8) void attn_kernel(
    const u64* __restrict__ qpack,
    const u64* __restrict__ kpackT,
    const unsigned short* __restrict__ vT,
    const int* __restrict__ Ti,
    unsigned short* __restrict__ ctx_hi,
    unsigned short* __restrict__ ctx_lo)
{
    __shared__ __align__(16) float praw[4352];   // 17408 B (8 rows x 544 f32)
    __shared__ __align__(16) u64 qw[8][20];      // 1280 B q-word cache
    unsigned short* pb = (unsigned short*)praw;  // overlay: p_bf16 [16][520]

    int tid = threadIdx.x;
    int bid = blockIdx.x;
    int swz = (bid & 7) * 256 + (bid >> 3);      // XCD-bijective
    int bh = swz >> 6;                 // 0..31
    int i0 = (swz & 63) << 3;          // 8-row group
    int b = bh >> 3, h = bh & 7;

    // ---- maxT over the 8 q-rows (wave-uniform scalar loads; EXACT clamp) --
    int maxT = 1;
    {
        const int* tp = Ti + b * 512 + i0;
#pragma unroll
        for (int i = 0; i < 8; ++i) maxT = max(maxT, tp[i]);
    }

    // ---- Phase 0: stage q-words (160 contiguous u64) ----------------------
    {
        const u64* qsrc = qpack + ((size_t)bh * 512 + i0) * TMAX;
        if (tid < 160) ((u64*)qw)[tid] = qsrc[tid];
    }
    __syncthreads();

    // ---- Phase 1: scores; thread owns columns j = tid AND j+256 -----------
    {
        int j = tid;
        const u64* kc0 = kpackT + (size_t)bh * TMAX * 512 + j;
        const u64* kc1 = kc0 + 256;
        int acc0[8], acc1[8];
#pragma unroll
        for (int i = 0; i < 8; ++i) { acc0[i] = 0; acc1[i] = 0; }

#define SUPERPASS(T0)                                                          \
        {                                                                      \
            u64 ka[4], kb[4];                                                  \
            _Pragma("unroll")                                                  \
            for (int t = 0; t < 4; ++t) {                                      \
                ka[t] = kc0[(size_t)(T0 + t) * 512];                           \
                kb[t] = kc1[(size_t)(T0 + t) * 512];                           \
            }                                                                  \
            _Pragma("unroll")                                                  \
            for (int i = 0; i < 8; ++i) {                                      \
                ulonglong2 qa = *(const ulonglong2*)&qw[i][T0];                \
                ulonglong2 qb2 = *(const ulonglong2*)&qw[i][(T0) + 2];         \
                acc0[i] += __popcll(qa.x & ka[0]) + __popcll(qa.y & ka[1])     \
                         + __popcll(qb2.x & ka[2]) + __popcll(qb2.y & ka[3]);  \
                acc1[i] += __popcll(qa.x & kb[0]) + __popcll(qa.y & kb[1])     \
                         + __popcll(qb2.x & kb[2]) + __popcll(qb2.y & kb[3]);  \
            }                                                                  \
        }

        SUPERPASS(0)
        if (maxT > 4)  SUPERPASS(4)
        if (maxT > 8)  SUPERPASS(8)
        if (maxT > 12) SUPERPASS(12)
        if (maxT > 16) SUPERPASS(16)
#undef SUPERPASS

#pragma unroll
        for (int i = 0; i < 8; ++i) {
            praw[i * 544 + j]       = 0.125f * (float)acc0[i];
            praw[i * 544 + 256 + j] = 0.125f * (float)acc1[i];
        }
    }
    __syncthreads();

    // ---- Phase 2: softmax (8 rows x 32 lanes); p -> bf16 with 0.05/lsum ---
    {
        int row = tid >> 5, jc = tid & 31;
        float pv[16];
        float m = -1e30f;
#pragma unroll
        for (int s = 0; s < 16; ++s) {
            pv[s] = praw[row * 544 + jc + s * 32];
            m = fmaxf(m, pv[s]);
        }
#pragma unroll
        for (int o = 1; o < 32; o <<= 1) m = fmaxf(m, __shfl_xor(m, o));
        float lsum = 0.f;
#pragma unroll
        for (int s = 0; s < 16; ++s) {
            pv[s] = __expf(pv[s] - m);
            lsum += pv[s];
        }
#pragma unroll
        for (int o = 1; o < 32; o <<= 1) lsum += __shfl_xor(lsum, o);
        float inv = 0.05f / lsum;                  // includes the /TMAX of v_mean
        __syncthreads();   // ALL praw reads complete before pb overlay writes
#pragma unroll
        for (int s = 0; s < 16; ++s)
            pb[row * 520 + jc + s * 32] = f2bf(pv[s] * inv);
    }
    __syncthreads();

    // ---- Phase 3: PV via MFMA; wave w -> d-chunk [w*16, w*16+16) ----------
    {
        int wv = tid >> 6, lane = tid & 63;
        int d0 = wv * 16;
        const unsigned short* vrow =
            vT + ((size_t)bh * 64 + d0 + (lane & 15)) * 512 + (lane >> 4) * 8;
        const unsigned short* prow = pb + (lane & 15) * 520 + (lane >> 4) * 8;
        f4a acc = {0.f, 0.f, 0.f, 0.f};
#pragma unroll
        for (int ks = 0; ks < 16; ++ks) {
            bf8 af = *(const bf8*)(vrow + ks * 32);
            bf8 bf_ = *(const bf8*)(prow + ks * 32);
            acc = __builtin_amdgcn_mfma_f32_16x16x32_bf16(af, bf_, acc, 0, 0, 0);
        }
        // D: col = lane&15 = i (rows 0-7 valid), row = (lane>>4)*4+r = d
        int ic = lane & 15;
        if (ic < 8) {
            int dloc = d0 + (lane >> 4) * 4;
            ushort4 h4, l4;
            split1(acc[0], h4.x, l4.x);
            split1(acc[1], h4.y, l4.y);
            split1(acc[2], h4.z, l4.z);
            split1(acc[3], h4.w, l4.w);
            size_t off = ((size_t)(b * 512 + i0 + ic)) * 512 + h * 64 + dloc;
            *(ushort4*)&ctx_hi[off] = h4;
            *(ushort4*)&ctx_lo[off] = l4;
        }
    }
}

// ---------------------------------------------------------------------------
extern "C" void kernel_launch(void* const* d_in, const int* in_sizes, int n_in,
                              void* d_out, int out_size, void* d_ws, size_t ws_size,
                              hipStream_t stream) {
    const float* x   = (const float*)d_in[0];
    const float* Wq  = (const float*)d_in[1];
    const float* Wk  = (const float*)d_in[2];
    const float* Wv  = (const float*)d_in[3];
    const float* Wo  = (const float*)d_in[4];
    const float* bo  = (const float*)d_in[5];
    const float* g1  = (const float*)d_in[6];
    const float* gb1 = (const float*)d_in[7];
    const float* g2  = (const float*)d_in[8];
    const float* gb2 = (const float*)d_in[9];
    const float* g3  = (const float*)d_in[10];
    const float* gb3 = (const float*)d_in[11];
    const float* c1  = (const float*)d_in[12];
    const float* cb1 = (const float*)d_in[13];
    const float* c2  = (const float*)d_in[14];
    const float* cb2 = (const float*)d_in[15];
    const float* alpha = (const float*)d_in[16];
    const float* beta  = (const float*)d_in[17];
    float* out = (float*)d_out;

    char* w = (char*)d_ws;
    float* q    = (float*)w;                         w += (size_t)BS * E_ * 4;
    float* kbuf = (float*)w;                         w += (size_t)BS * E_ * 4;  // later ctx_hi/lo
    float* vbuf = (float*)w;                         w += (size_t)BS * E_ * 4;
    int* Ti     = (int*)w;                           w += (size_t)BS * 4;
    u64* qpack  = (u64*)w;                           w += (size_t)BS * NH * TMAX * 8;  // first: x_hi
    u64* kpackT = (u64*)w;                           w += (size_t)BS * NH * TMAX * 8;  // first: x_lo
    char* vregion = w;                               w += (size_t)BS * E_ * 4;  // wtqkv -> vcnt+vT
    unsigned short* wto_hi = (unsigned short*)w;     w += (size_t)512 * 512 * 2;
    unsigned short* wto_lo = (unsigned short*)w;     w += (size_t)512 * 512 * 2;

    unsigned short* x_hi = (unsigned short*)qpack;
    unsigned short* x_lo = (unsigned short*)kpackT;
    unsigned short* wtqkv_hi = (unsigned short*)vregion;               // 1.5 MB
    unsigned short* wtqkv_lo = (unsigned short*)vregion + (size_t)3 * 512 * 512;
    unsigned short* vcnt = (unsigned short*)vregion;                   // 2 MB (after gemm)
    unsigned short* vT   = (unsigned short*)vregion + (size_t)BS * E_; // 2 MB
    unsigned short* ctx_hi = (unsigned short*)kbuf;
    unsigned short* ctx_lo = (unsigned short*)kbuf + (size_t)BS * E_;

    // 1) split x; transpose+split all W
    xsplit_kernel<<<1024, 256, 0, stream>>>(x, x_hi, x_lo);
    wsplit_kernel<<<dim3(8, 8, 4), 256, 0, stream>>>(Wq, Wk, Wv, Wo,
                                                     wtqkv_hi, wtqkv_lo, wto_hi, wto_lo);
    // 2) qkv projections (LDS-staged, 128x128 tile, 2-phase dbuf)
    gemm_lds_kernel<<<dim3(4, 16, 3), 256, 0, stream>>>(x_hi, x_lo,
        wtqkv_hi, wtqkv_lo, q, nullptr, 512 * 512, BS * E_);
    // 3) windows
    mlp_gate_kernel<<<1024, 256, 0, stream>>>(x, g1, gb1, g2, gb2, g3, gb3,
                                              c1, cb1, c2, cb2, Ti);
    // 4) LIF (overwrites x_hi/lo and wtqkv regions - stream-ordered after gemm)
    lif_kernel<<<dim3(4096, 3), 256, 0, stream>>>(q, kbuf, vbuf, Ti, alpha, beta,
                                                  qpack, kpackT, vcnt);
    // 5) V transpose to [bh][d][j] bf16
    vtrans_kernel<<<dim3(8, 32), 256, 0, stream>>>(vcnt, vT);
    // 6) attention (emits ctx hi/lo bf16 directly)
    attn_kernel<<<2048, 256, 0, stream>>>(qpack, kpackT, vT, Ti, ctx_hi, ctx_lo);
    // 7) output projection (LDS-staged, 128x128 tile, 2-phase dbuf)
    gemm_lds_kernel<<<dim3(4, 16, 1), 256, 0, stream>>>(ctx_hi, ctx_lo,
        wto_hi, wto_lo, out, bo, 0, 0);
}

// Round 18
// 106.041 us; speedup vs baseline: 1.0888x; 1.0888x over previous
//
#include <hip/hip_runtime.h>
#include <stdint.h>

#define BS 2048   // B*S
#define E_ 512
#define NH 8
#define HD 64
#define TMAX 20

typedef unsigned long long u64;

using bf8   = __attribute__((ext_vector_type(8))) short;          // 8 bf16
using f4a   = __attribute__((ext_vector_type(4))) float;          // 4 f32 acc
using u16x8 = __attribute__((ext_vector_type(8))) unsigned short;

// ---------------------------------------------------------------------------
// f32 <-> bf16 split helpers (RNE)
// ---------------------------------------------------------------------------
__device__ __forceinline__ unsigned short f2bf(float f) {
    unsigned u = __float_as_uint(f);
    return (unsigned short)((u + 0x7FFFu + ((u >> 16) & 1u)) >> 16);
}
__device__ __forceinline__ float bf2f(unsigned short h) {
    return __uint_as_float(((unsigned)h) << 16);
}
__device__ __forceinline__ void split1(float x, unsigned short& h, unsigned short& l) {
    h = f2bf(x);
    l = f2bf(x - bf2f(h));
}

__device__ __forceinline__ void load_lds16(const void* g, void* l) {
    __builtin_amdgcn_global_load_lds(
        (const __attribute__((address_space(1))) void*)g,
        (__attribute__((address_space(3))) void*)l, 16, 0, 0);
}

// ---------------------------------------------------------------------------
// split x: f32 [n] -> hi/lo bf16. n = BS*E_ = 1M, grid 1024x256 (float4)
// ---------------------------------------------------------------------------
__global__ __launch_bounds__(256) void xsplit_kernel(const float* __restrict__ src,
    unsigned short* __restrict__ hi, unsigned short* __restrict__ lo)
{
    int i = blockIdx.x * 256 + threadIdx.x;
    float4 v = ((const float4*)src)[i];
    ushort4 h, l;
    split1(v.x, h.x, l.x);
    split1(v.y, h.y, l.y);
    split1(v.z, h.z, l.z);
    split1(v.w, h.w, l.w);
    ((ushort4*)hi)[i] = h;
    ((ushort4*)lo)[i] = l;
}

// ---------------------------------------------------------------------------
// transpose + split W: W[k][n] f32 -> Wt_hi/lo[n][k] bf16. grid (8,8,4) 256thr
// ---------------------------------------------------------------------------
__global__ __launch_bounds__(256) void wsplit_kernel(
    const float* __restrict__ Wq, const float* __restrict__ Wk,
    const float* __restrict__ Wv, const float* __restrict__ Wo,
    unsigned short* __restrict__ qkv_hi, unsigned short* __restrict__ qkv_lo,
    unsigned short* __restrict__ o_hi, unsigned short* __restrict__ o_lo)
{
    __shared__ float t[64][65];
    int z = blockIdx.z;
    const float* W = (z == 0) ? Wq : (z == 1) ? Wk : (z == 2) ? Wv : Wo;
    unsigned short* dhi = (z < 3) ? qkv_hi + (size_t)z * 512 * 512 : o_hi;
    unsigned short* dlo = (z < 3) ? qkv_lo + (size_t)z * 512 * 512 : o_lo;
    int k0 = blockIdx.y * 64, n0 = blockIdx.x * 64;
    int tid = threadIdx.x;
    int r = tid >> 4, c4 = (tid & 15) * 4;
#pragma unroll
    for (int j = 0; j < 4; ++j) {
        int row = r + j * 16;
        float4 v = *(const float4*)&W[(size_t)(k0 + row) * 512 + n0 + c4];
        t[row][c4 + 0] = v.x; t[row][c4 + 1] = v.y;
        t[row][c4 + 2] = v.z; t[row][c4 + 3] = v.w;
    }
    __syncthreads();
#pragma unroll
    for (int j = 0; j < 4; ++j) {
        int n = r + j * 16;
        ushort4 h, l;
        split1(t[c4 + 0][n], h.x, l.x);
        split1(t[c4 + 1][n], h.y, l.y);
        split1(t[c4 + 2][n], h.z, l.z);
        split1(t[c4 + 3][n], h.w, l.w);
        *(ushort4*)&dhi[(size_t)(n0 + n) * 512 + k0 + c4] = h;
        *(ushort4*)&dlo[(size_t)(n0 + n) * 512 + k0 + c4] = l;
    }
}

// ---------------------------------------------------------------------------
// LDS-staged split-bf16 MFMA GEMM (3-term), 64x64 tile, BK=32, 2-PHASE dbuf
// (round-15 structure, known-good). Optional K-SPLIT=2: blockIdx.z encodes
// (z, ks); each half-K block writes its partial to Cbase + ks*kpart_stride;
// the consumer (lif) sums the two partials -> no add kernel, +2x grid.
// ---------------------------------------------------------------------------
__global__ __launch_bounds__(256) void gemm_lds_kernel(
    const unsigned short* __restrict__ Ag_hi, const unsigned short* __restrict__ Ag_lo,
    const unsigned short* __restrict__ Bg_hi, const unsigned short* __restrict__ Bg_lo,
    float* __restrict__ Cbase, const float* __restrict__ bias,
    int zstride_b, int zstride_c, long kpart_stride, int ksplit)
{
    __shared__ __align__(16) unsigned short lds[2][4][2048];   // 32 KB

    int bz = blockIdx.z;
    int z  = (ksplit == 2) ? (bz >> 1) : bz;
    int ks = (ksplit == 2) ? (bz & 1) : 0;
    int kbeg = ks * 256;
    int kend = kbeg + ((ksplit == 2) ? 256 : 512);

    const unsigned short* bhg = Bg_hi + (size_t)z * zstride_b;
    const unsigned short* blg = Bg_lo + (size_t)z * zstride_b;
    float* C = Cbase + (size_t)z * zstride_c + (size_t)ks * kpart_stride;

    int tid = threadIdx.x;
    int w = tid >> 6, lane = tid & 63;
    int m0 = blockIdx.y * 64, n0 = blockIdx.x * 64;
    int wr = w >> 1, wc = w & 1;
    int fr = lane & 15, g8 = lane >> 4;

    int c = w * 64 + lane;
    int srow = c >> 2;
    int scol = (c & 3) ^ (srow & 3);
    unsigned lb = (unsigned)(w * 64) * 8;

    f4a z4 = {0.f, 0.f, 0.f, 0.f};
    f4a acc00 = z4, acc01 = z4, acc10 = z4, acc11 = z4;

    int ra0 = wr * 32 + fr, ra1 = ra0 + 16;
    int rb0 = wc * 32 + fr, rb1 = rb0 + 16;

#define STAGE(ph, k0)                                                         \
    {                                                                         \
        size_t ga = (size_t)(m0 + srow) * 512 + (k0) + scol * 8;              \
        size_t gb = (size_t)(n0 + srow) * 512 + (k0) + scol * 8;              \
        load_lds16(Ag_hi + ga, &lds[ph][0][lb]);                              \
        load_lds16(Ag_lo + ga, &lds[ph][1][lb]);                              \
        load_lds16(bhg + gb, &lds[ph][2][lb]);                                \
        load_lds16(blg + gb, &lds[ph][3][lb]);                                \
    }

#define FRAG(ph, buf, row) (*(const bf8*)&lds[ph][buf][(row) * 32 + (((g8) ^ ((row) & 3)) << 3)])

    STAGE(0, kbeg);
    __syncthreads();
    int ph = 0;
#pragma unroll 1
    for (int k0 = kbeg; k0 < kend; k0 += 32) {
        if (k0 + 32 < kend) STAGE(ph ^ 1, k0 + 32);
        bf8 fah0 = FRAG(ph, 0, ra0);
        bf8 fah1 = FRAG(ph, 0, ra1);
        bf8 fal0 = FRAG(ph, 1, ra0);
        bf8 fal1 = FRAG(ph, 1, ra1);
        bf8 fbh0 = FRAG(ph, 2, rb0);
        bf8 fbh1 = FRAG(ph, 2, rb1);
        bf8 fbl0 = FRAG(ph, 3, rb0);
        bf8 fbl1 = FRAG(ph, 3, rb1);
        acc00 = __builtin_amdgcn_mfma_f32_16x16x32_bf16(fah0, fbh0, acc00, 0, 0, 0);
        acc01 = __builtin_amdgcn_mfma_f32_16x16x32_bf16(fah0, fbh1, acc01, 0, 0, 0);
        acc10 = __builtin_amdgcn_mfma_f32_16x16x32_bf16(fah1, fbh0, acc10, 0, 0, 0);
        acc11 = __builtin_amdgcn_mfma_f32_16x16x32_bf16(fah1, fbh1, acc11, 0, 0, 0);
        acc00 = __builtin_amdgcn_mfma_f32_16x16x32_bf16(fah0, fbl0, acc00, 0, 0, 0);
        acc01 = __builtin_amdgcn_mfma_f32_16x16x32_bf16(fah0, fbl1, acc01, 0, 0, 0);
        acc10 = __builtin_amdgcn_mfma_f32_16x16x32_bf16(fah1, fbl0, acc10, 0, 0, 0);
        acc11 = __builtin_amdgcn_mfma_f32_16x16x32_bf16(fah1, fbl1, acc11, 0, 0, 0);
        acc00 = __builtin_amdgcn_mfma_f32_16x16x32_bf16(fal0, fbh0, acc00, 0, 0, 0);
        acc01 = __builtin_amdgcn_mfma_f32_16x16x32_bf16(fal0, fbh1, acc01, 0, 0, 0);
        acc10 = __builtin_amdgcn_mfma_f32_16x16x32_bf16(fal1, fbh0, acc10, 0, 0, 0);
        acc11 = __builtin_amdgcn_mfma_f32_16x16x32_bf16(fal1, fbh1, acc11, 0, 0, 0);
        __syncthreads();
        ph ^= 1;
    }
#undef STAGE
#undef FRAG

    int col0 = n0 + wc * 32 + fr, col1 = col0 + 16;
    int rbase0 = m0 + wr * 32 + g8 * 4;
    int rbase1 = rbase0 + 16;
    float b0 = bias ? bias[col0] : 0.f;
    float b1 = bias ? bias[col1] : 0.f;
#pragma unroll
    for (int r = 0; r < 4; ++r) {
        C[(size_t)(rbase0 + r) * 512 + col0] = acc00[r] + b0;
        C[(size_t)(rbase0 + r) * 512 + col1] = acc01[r] + b1;
        C[(size_t)(rbase1 + r) * 512 + col0] = acc10[r] + b0;
        C[(size_t)(rbase1 + r) * 512 + col1] = acc11[r] + b1;
    }
}

// ---------------------------------------------------------------------------
// Gate/complexity MLPs -> T_i. 2 tokens per 256-thread block, 1024 blocks.
// ---------------------------------------------------------------------------
__global__ __launch_bounds__(256) void mlp_gate_kernel(const float* __restrict__ x,
    const float* __restrict__ g1, const float* __restrict__ gb1,
    const float* __restrict__ g2, const float* __restrict__ gb2,
    const float* __restrict__ g3, const float* __restrict__ gb3,
    const float* __restrict__ c1, const float* __restrict__ cb1,
    const float* __restrict__ c2, const float* __restrict__ cb2,
    int* __restrict__ Ti)
{
    __shared__ __align__(16) float xsh[2][512];
    __shared__ float p1[2][4][64];
    __shared__ float h1sh[2][64];
    __shared__ float p2[2][4][32];
    __shared__ float gsh[2];
    int tid = threadIdx.x;
    int tok0 = blockIdx.x * 2;

    ((float4*)&xsh[0][0])[tid] = ((const float4*)&x[(size_t)tok0 * 512])[tid];
    __syncthreads();

    {
        int l = tid & 63, ec = tid >> 6;
        float a0 = 0.f, a1 = 0.f;
        int e0 = ec * 128;
#pragma unroll 8
        for (int t = 0; t < 128; ++t) {
            int e = e0 + t;
            float w = g1[e * 64 + l];
            a0 = fmaf(xsh[0][e], w, a0);
            a1 = fmaf(xsh[1][e], w, a1);
        }
        p1[0][ec][l] = a0;
        p1[1][ec][l] = a1;
    }
    __syncthreads();
    if (tid < 128) {
        int tok = tid >> 6, l = tid & 63;
        float h = p1[tok][0][l] + p1[tok][1][l] + p1[tok][2][l] + p1[tok][3][l] + gb1[l];
        h1sh[tok][l] = fmaxf(h, 0.f);
    }
    __syncthreads();
    {
        int m = tid & 31, g = tid >> 5, tok = g & 1, lc = g >> 1;
        float a = 0.f;
#pragma unroll
        for (int t = 0; t < 16; ++t) {
            int l = lc * 16 + t;
            a = fmaf(h1sh[tok][l], g2[l * 32 + m], a);
        }
        p2[tok][lc][m] = a;
    }
    __syncthreads();
    if (tid < 64) {
        int tok = tid >> 5, m = tid & 31;
        float h = p2[tok][0][m] + p2[tok][1][m] + p2[tok][2][m] + p2[tok][3][m] + gb2[m];
        h = fmaxf(h, 0.f);
        float v = h * g3[m];
#pragma unroll
        for (int o = 1; o < 32; o <<= 1) v += __shfl_xor(v, o);
        if (m == 0) gsh[tok] = 1.f / (1.f + expf(-(v + gb3[0])));
    }
    __syncthreads();
    {
        int m = tid & 31, g = tid >> 5, tok = g & 1, ec = g >> 1;
        float a = 0.f;
        int e0 = ec * 128;
#pragma unroll 8
        for (int t = 0; t < 128; ++t) {
            int e = e0 + t;
            a = fmaf(xsh[tok][e], c1[e * 32 + m], a);
        }
        p2[tok][ec][m] = a;
    }
    __syncthreads();
    if (tid < 64) {
        int tok = tid >> 5, m = tid & 31;
        float h = p2[tok][0][m] + p2[tok][1][m] + p2[tok][2][m] + p2[tok][3][m] + cb1[m];
        h = fmaxf(h, 0.f);
        float v = h * c2[m];
#pragma unroll
        for (int o = 1; o < 32; o <<= 1) v += __shfl_xor(v, o);
        if (m == 0) {
            float comp = 1.f / (1.f + expf(-(v + cb2[0])));
            float comb = 0.7f * gsh[tok] + 0.3f * comp;
            int t = (int)ceilf(comb * 20.f);
            t = t < 1 ? 1 : (t > 20 ? 20 : t);
            Ti[tok0 + tok] = t;
        }
    }
}

// ---------------------------------------------------------------------------
// LIF + window mask. One wave per (token, head). lane = channel within head.
// Input = SUM of the two K-split GEMM partials (p0 + p1) -- the K-split
// reduction is fused here for free.
// mode 0 (q): qpack[bh*512+i][t]  mode 1 (k): kpackT[bh][t][j]
// mode 2 (v): spike count as exact bf16 integer.
// ---------------------------------------------------------------------------
__global__ __launch_bounds__(256) void lif_kernel(
    const float* __restrict__ qkv_p0, const float* __restrict__ qkv_p1,
    const int* __restrict__ Ti,
    const float* __restrict__ alphap, const float* __restrict__ betap,
    u64* __restrict__ qpack, u64* __restrict__ kpackT,
    unsigned short* __restrict__ vcnt_bf16)
{
    int mode = blockIdx.y;
    const float* s0 = qkv_p0 + (size_t)mode * BS * E_;
    const float* s1 = qkv_p1 + (size_t)mode * BS * E_;
    int w = blockIdx.x * 4 + (threadIdx.x >> 6);   // 0..16383
    int lane = threadIdx.x & 63;
    int token = w >> 3;
    int h = w & 7;
    size_t idx = (size_t)token * 512 + h * 64 + lane;
    float xin = s0[idx] + s1[idx];
    int T = Ti[token];
    float alpha = alphap[0], beta = betap[0];
    float vm = 0.f, isyn = 0.f;
    u64 myword = 0ull;
    int cnt = 0;
#pragma unroll
    for (int t = 0; t < TMAX; ++t) {
        isyn = alpha * isyn + xin;
        vm = beta * vm + isyn;
        bool sp = vm >= 1.0f;
        if (sp) vm = 0.f;
        bool msk = sp && (t < T);
        if (mode < 2) {
            u64 word = __ballot(msk ? 1 : 0);
            if (lane == t) myword = word;
        } else {
            cnt += msk ? 1 : 0;
        }
    }
    int b = token >> 9, i = token & 511;
    size_t bh = (size_t)(b * 8 + h);
    if (mode == 0) { if (lane < TMAX) qpack[(bh * 512 + i) * TMAX + lane] = myword; }
    else if (mode == 1) { if (lane < TMAX) kpackT[(bh * TMAX + lane) * 512 + i] = myword; }
    else { vcnt_bf16[(bh * 512 + i) * 64 + lane] = f2bf((float)cnt); }  // exact
}

// ---------------------------------------------------------------------------
// transpose vcnt: [bh][j][d] u16 -> vT[bh][d][j] u16. grid (8 jchunks, 32 bh).
// ---------------------------------------------------------------------------
__global__ __launch_bounds__(256) void vtrans_kernel(
    const unsigned short* __restrict__ vin, unsigned short* __restrict__ vout)
{
    __shared__ unsigned short t[64][80];   // pad 80: 16B-aligned rows
    int bh = blockIdx.y, j0 = blockIdx.x * 64;
    int tid = threadIdx.x;
    {
        int jl = tid >> 2, dc = (tid & 3) * 16;
        const unsigned short* src = vin + ((size_t)bh * 512 + j0 + jl) * 64 + dc;
        u16x8 a = *(const u16x8*)src;
        u16x8 b = *(const u16x8*)(src + 8);
#pragma unroll
        for (int k = 0; k < 8; ++k) t[dc + k][jl] = a[k];
#pragma unroll
        for (int k = 0; k < 8; ++k) t[dc + 8 + k][jl] = b[k];
    }
    __syncthreads();
    {
        int dl = tid >> 2, jc = (tid & 3) * 16;
        u16x8 o0 = *(const u16x8*)&t[dl][jc];
        u16x8 o1 = *(const u16x8*)&t[dl][jc + 8];
        unsigned short* dst = vout + ((size_t)bh * 64 + dl) * 512 + j0 + jc;
        *(u16x8*)dst = o0;
        *(u16x8*)(dst + 8) = o1;
    }
}

// ---------------------------------------------------------------------------
// attn: 256 threads (4 waves), 2048 blocks, LDS 18688 B -> 8 blocks/CU.
// (unchanged from round 15)
// ---------------------------------------------------------------------------
__global__ __launch_bounds__(256, 8) void attn_kernel(
    const u64* __restrict__ qpack,
    const u64* __restrict__ kpackT,
    const unsigned short* __restrict__ vT,
    const int* __restrict__ Ti,
    unsigned short* __restrict__ ctx_hi,
    unsigned short* __restrict__ ctx_lo)
{
    __shared__ __align__(16) float praw[4352];   // 17408 B (8 rows x 544 f32)
    __shared__ __align__(16) u64 qw[8][20];      // 1280 B q-word cache
    unsigned short* pb = (unsigned short*)praw;  // overlay: p_bf16 [16][520]

    int tid = threadIdx.x;
    int bid = blockIdx.x;
    int swz = (bid & 7) * 256 + (bid >> 3);      // XCD-bijective
    int bh = swz >> 6;                 // 0..31
    int i0 = (swz & 63) << 3;          // 8-row group
    int b = bh >> 3, h = bh & 7;

    // ---- maxT over the 8 q-rows (wave-uniform scalar loads; EXACT clamp) --
    int maxT = 1;
    {
        const int* tp = Ti + b * 512 + i0;
#pragma unroll
        for (int i = 0; i < 8; ++i) maxT = max(maxT, tp[i]);
    }

    // ---- Phase 0: stage q-words (160 contiguous u64) ----------------------
    {
        const u64* qsrc = qpack + ((size_t)bh * 512 + i0) * TMAX;
        if (tid < 160) ((u64*)qw)[tid] = qsrc[tid];
    }
    __syncthreads();

    // ---- Phase 1: scores; thread owns columns j = tid AND j+256 -----------
    {
        int j = tid;
        const u64* kc0 = kpackT + (size_t)bh * TMAX * 512 + j;
        const u64* kc1 = kc0 + 256;
        int acc0[8], acc1[8];
#pragma unroll
        for (int i = 0; i < 8; ++i) { acc0[i] = 0; acc1[i] = 0; }

#define SUPERPASS(T0)                                                          \
        {                                                                      \
            u64 ka[4], kb[4];                                                  \
            _Pragma("unroll")                                                  \
            for (int t = 0; t < 4; ++t) {                                      \
                ka[t] = kc0[(size_t)(T0 + t) * 512];                           \
                kb[t] = kc1[(size_t)(T0 + t) * 512];                           \
            }                                                                  \
            _Pragma("unroll")                                                  \
            for (int i = 0; i < 8; ++i) {                                      \
                ulonglong2 qa = *(const ulonglong2*)&qw[i][T0];                \
                ulonglong2 qb2 = *(const ulonglong2*)&qw[i][(T0) + 2];         \
                acc0[i] += __popcll(qa.x & ka[0]) + __popcll(qa.y & ka[1])     \
                         + __popcll(qb2.x & ka[2]) + __popcll(qb2.y & ka[3]);  \
                acc1[i] += __popcll(qa.x & kb[0]) + __popcll(qa.y & kb[1])     \
                         + __popcll(qb2.x & kb[2]) + __popcll(qb2.y & kb[3]);  \
            }                                                                  \
        }

        SUPERPASS(0)
        if (maxT > 4)  SUPERPASS(4)
        if (maxT > 8)  SUPERPASS(8)
        if (maxT > 12) SUPERPASS(12)
        if (maxT > 16) SUPERPASS(16)
#undef SUPERPASS

#pragma unroll
        for (int i = 0; i < 8; ++i) {
            praw[i * 544 + j]       = 0.125f * (float)acc0[i];
            praw[i * 544 + 256 + j] = 0.125f * (float)acc1[i];
        }
    }
    __syncthreads();

    // ---- Phase 2: softmax (8 rows x 32 lanes); p -> bf16 with 0.05/lsum ---
    {
        int row = tid >> 5, jc = tid & 31;
        float pv[16];
        float m = -1e30f;
#pragma unroll
        for (int s = 0; s < 16; ++s) {
            pv[s] = praw[row * 544 + jc + s * 32];
            m = fmaxf(m, pv[s]);
        }
#pragma unroll
        for (int o = 1; o < 32; o <<= 1) m = fmaxf(m, __shfl_xor(m, o));
        float lsum = 0.f;
#pragma unroll
        for (int s = 0; s < 16; ++s) {
            pv[s] = __expf(pv[s] - m);
            lsum += pv[s];
        }
#pragma unroll
        for (int o = 1; o < 32; o <<= 1) lsum += __shfl_xor(lsum, o);
        float inv = 0.05f / lsum;                  // includes the /TMAX of v_mean
        __syncthreads();   // ALL praw reads complete before pb overlay writes
#pragma unroll
        for (int s = 0; s < 16; ++s)
            pb[row * 520 + jc + s * 32] = f2bf(pv[s] * inv);
    }
    __syncthreads();

    // ---- Phase 3: PV via MFMA; wave w -> d-chunk [w*16, w*16+16) ----------
    {
        int wv = tid >> 6, lane = tid & 63;
        int d0 = wv * 16;
        const unsigned short* vrow =
            vT + ((size_t)bh * 64 + d0 + (lane & 15)) * 512 + (lane >> 4) * 8;
        const unsigned short* prow = pb + (lane & 15) * 520 + (lane >> 4) * 8;
        f4a acc = {0.f, 0.f, 0.f, 0.f};
#pragma unroll
        for (int ks = 0; ks < 16; ++ks) {
            bf8 af = *(const bf8*)(vrow + ks * 32);
            bf8 bf_ = *(const bf8*)(prow + ks * 32);
            acc = __builtin_amdgcn_mfma_f32_16x16x32_bf16(af, bf_, acc, 0, 0, 0);
        }
        // D: col = lane&15 = i (rows 0-7 valid), row = (lane>>4)*4+r = d
        int ic = lane & 15;
        if (ic < 8) {
            int dloc = d0 + (lane >> 4) * 4;
            ushort4 h4, l4;
            split1(acc[0], h4.x, l4.x);
            split1(acc[1], h4.y, l4.y);
            split1(acc[2], h4.z, l4.z);
            split1(acc[3], h4.w, l4.w);
            size_t off = ((size_t)(b * 512 + i0 + ic)) * 512 + h * 64 + dloc;
            *(ushort4*)&ctx_hi[off] = h4;
            *(ushort4*)&ctx_lo[off] = l4;
        }
    }
}

// ---------------------------------------------------------------------------
extern "C" void kernel_launch(void* const* d_in, const int* in_sizes, int n_in,
                              void* d_out, int out_size, void* d_ws, size_t ws_size,
                              hipStream_t stream) {
    const float* x   = (const float*)d_in[0];
    const float* Wq  = (const float*)d_in[1];
    const float* Wk  = (const float*)d_in[2];
    const float* Wv  = (const float*)d_in[3];
    const float* Wo  = (const float*)d_in[4];
    const float* bo  = (const float*)d_in[5];
    const float* g1  = (const float*)d_in[6];
    const float* gb1 = (const float*)d_in[7];
    const float* g2  = (const float*)d_in[8];
    const float* gb2 = (const float*)d_in[9];
    const float* g3  = (const float*)d_in[10];
    const float* gb3 = (const float*)d_in[11];
    const float* c1  = (const float*)d_in[12];
    const float* cb1 = (const float*)d_in[13];
    const float* c2  = (const float*)d_in[14];
    const float* cb2 = (const float*)d_in[15];
    const float* alpha = (const float*)d_in[16];
    const float* beta  = (const float*)d_in[17];
    float* out = (float*)d_out;

    char* w = (char*)d_ws;
    float* qkv_p0 = (float*)w;                       w += (size_t)3 * BS * E_ * 4;  // 12 MB
    float* qkv_p1 = (float*)w;                       w += (size_t)3 * BS * E_ * 4;  // 12 MB
    int* Ti     = (int*)w;                           w += (size_t)BS * 4;
    u64* qpack  = (u64*)w;                           w += (size_t)BS * NH * TMAX * 8;  // first: x_hi
    u64* kpackT = (u64*)w;                           w += (size_t)BS * NH * TMAX * 8;  // first: x_lo
    char* vregion = w;                               w += (size_t)BS * E_ * 4;  // wtqkv -> vcnt+vT
    unsigned short* wto_hi = (unsigned short*)w;     w += (size_t)512 * 512 * 2;
    unsigned short* wto_lo = (unsigned short*)w;     w += (size_t)512 * 512 * 2;

    unsigned short* x_hi = (unsigned short*)qpack;
    unsigned short* x_lo = (unsigned short*)kpackT;
    unsigned short* wtqkv_hi = (unsigned short*)vregion;               // 1.5 MB
    unsigned short* wtqkv_lo = (unsigned short*)vregion + (size_t)3 * 512 * 512;
    unsigned short* vcnt = (unsigned short*)vregion;                   // 2 MB (after gemm)
    unsigned short* vT   = (unsigned short*)vregion + (size_t)BS * E_; // 2 MB
    // ctx hi/lo live in qkv_p0's region (free after lif consumes it)
    unsigned short* ctx_hi = (unsigned short*)qkv_p0;
    unsigned short* ctx_lo = (unsigned short*)qkv_p0 + (size_t)BS * E_;

    // 1) split x; transpose+split all W
    xsplit_kernel<<<1024, 256, 0, stream>>>(x, x_hi, x_lo);
    wsplit_kernel<<<dim3(8, 8, 4), 256, 0, stream>>>(Wq, Wk, Wv, Wo,
                                                     wtqkv_hi, wtqkv_lo, wto_hi, wto_lo);
    // 2) qkv projections: K-SPLIT=2 (grid z = 3 gemms x 2 K-halves = 6),
    //    partials to qkv_p0 / qkv_p1; lif fuses the sum.
    gemm_lds_kernel<<<dim3(8, 32, 6), 256, 0, stream>>>(x_hi, x_lo,
        wtqkv_hi, wtqkv_lo, qkv_p0, nullptr, 512 * 512, BS * E_,
        (long)3 * BS * E_, 2);
    // 3) windows
    mlp_gate_kernel<<<1024, 256, 0, stream>>>(x, g1, gb1, g2, gb2, g3, gb3,
                                              c1, cb1, c2, cb2, Ti);
    // 4) LIF (sums K-split partials; overwrites x_hi/lo + wtqkv after gemm)
    lif_kernel<<<dim3(4096, 3), 256, 0, stream>>>(qkv_p0, qkv_p1, Ti, alpha, beta,
                                                  qpack, kpackT, vcnt);
    // 5) V transpose to [bh][d][j] bf16
    vtrans_kernel<<<dim3(8, 32), 256, 0, stream>>>(vcnt, vT);
    // 6) attention (emits ctx hi/lo bf16 directly)
    attn_kernel<<<2048, 256, 0, stream>>>(qpack, kpackT, vT, Ti, ctx_hi, ctx_lo);
    // 7) output projection (full K, no split)
    gemm_lds_kernel<<<dim3(8, 32, 1), 256, 0, stream>>>(ctx_hi, ctx_lo,
        wto_hi, wto_lo, out, bo, 0, 0, 0, 1);
}

// Round 19
// 99.040 us; speedup vs baseline: 1.1658x; 1.0707x over previous
//
#include <hip/hip_runtime.h>
#include <stdint.h>

#define BS 2048   // B*S
#define E_ 512
#define NH 8
#define HD 64
#define TMAX 20

typedef unsigned long long u64;

using bf8   = __attribute__((ext_vector_type(8))) short;          // 8 bf16
using f4a   = __attribute__((ext_vector_type(4))) float;          // 4 f32 acc
using u16x8 = __attribute__((ext_vector_type(8))) unsigned short;

// ---------------------------------------------------------------------------
// f32 <-> bf16 split helpers (RNE)
// ---------------------------------------------------------------------------
__device__ __forceinline__ unsigned short f2bf(float f) {
    unsigned u = __float_as_uint(f);
    return (unsigned short)((u + 0x7FFFu + ((u >> 16) & 1u)) >> 16);
}
__device__ __forceinline__ float bf2f(unsigned short h) {
    return __uint_as_float(((unsigned)h) << 16);
}
__device__ __forceinline__ void split1(float x, unsigned short& h, unsigned short& l) {
    h = f2bf(x);
    l = f2bf(x - bf2f(h));
}

__device__ __forceinline__ void load_lds16(const void* g, void* l) {
    __builtin_amdgcn_global_load_lds(
        (const __attribute__((address_space(1))) void*)g,
        (__attribute__((address_space(3))) void*)l, 16, 0, 0);
}

// ---------------------------------------------------------------------------
// FUSED split kernel: blocks 0..1023 = xsplit (f32 -> hi/lo bf16, float4/thr);
// blocks 1024..1279 = wsplit (transpose+split one 64x64 tile of one W).
// Branch is block-uniform -> the __syncthreads in wsplit path is safe.
// ---------------------------------------------------------------------------
__global__ __launch_bounds__(256) void split_all_kernel(
    const float* __restrict__ x,
    const float* __restrict__ Wq, const float* __restrict__ Wk,
    const float* __restrict__ Wv, const float* __restrict__ Wo,
    unsigned short* __restrict__ x_hi, unsigned short* __restrict__ x_lo,
    unsigned short* __restrict__ qkv_hi, unsigned short* __restrict__ qkv_lo,
    unsigned short* __restrict__ o_hi, unsigned short* __restrict__ o_lo)
{
    __shared__ float t[64][65];
    int tid = threadIdx.x;
    int bidx = blockIdx.x;
    if (bidx < 1024) {
        int i = bidx * 256 + tid;
        float4 v = ((const float4*)x)[i];
        ushort4 h, l;
        split1(v.x, h.x, l.x);
        split1(v.y, h.y, l.y);
        split1(v.z, h.z, l.z);
        split1(v.w, h.w, l.w);
        ((ushort4*)x_hi)[i] = h;
        ((ushort4*)x_lo)[i] = l;
        return;
    }
    int wb = bidx - 1024;            // 0..255
    int z = wb >> 6;                 // 0..3
    int rem = wb & 63;
    int k0 = (rem >> 3) * 64, n0 = (rem & 7) * 64;
    const float* W = (z == 0) ? Wq : (z == 1) ? Wk : (z == 2) ? Wv : Wo;
    unsigned short* dhi = (z < 3) ? qkv_hi + (size_t)z * 512 * 512 : o_hi;
    unsigned short* dlo = (z < 3) ? qkv_lo + (size_t)z * 512 * 512 : o_lo;
    int r = tid >> 4, c4 = (tid & 15) * 4;
#pragma unroll
    for (int j = 0; j < 4; ++j) {
        int row = r + j * 16;
        float4 v = *(const float4*)&W[(size_t)(k0 + row) * 512 + n0 + c4];
        t[row][c4 + 0] = v.x; t[row][c4 + 1] = v.y;
        t[row][c4 + 2] = v.z; t[row][c4 + 3] = v.w;
    }
    __syncthreads();
#pragma unroll
    for (int j = 0; j < 4; ++j) {
        int n = r + j * 16;
        ushort4 h, l;
        split1(t[c4 + 0][n], h.x, l.x);
        split1(t[c4 + 1][n], h.y, l.y);
        split1(t[c4 + 2][n], h.z, l.z);
        split1(t[c4 + 3][n], h.w, l.w);
        *(ushort4*)&dhi[(size_t)(n0 + n) * 512 + k0 + c4] = h;
        *(ushort4*)&dlo[(size_t)(n0 + n) * 512 + k0 + c4] = l;
    }
}

// ---------------------------------------------------------------------------
// LDS-staged split-bf16 MFMA GEMM (3-term), 64x64 tile, BK=32, 2-PHASE dbuf
// (round-15 structure, known-good 102.1 us).
// ---------------------------------------------------------------------------
__global__ __launch_bounds__(256) void gemm_lds_kernel(
    const unsigned short* __restrict__ Ag_hi, const unsigned short* __restrict__ Ag_lo,
    const unsigned short* __restrict__ Bg_hi, const unsigned short* __restrict__ Bg_lo,
    float* __restrict__ Cbase, const float* __restrict__ bias,
    int zstride_b, int zstride_c)
{
    __shared__ __align__(16) unsigned short lds[2][4][2048];   // 32 KB

    int z = blockIdx.z;
    const unsigned short* bhg = Bg_hi + (size_t)z * zstride_b;
    const unsigned short* blg = Bg_lo + (size_t)z * zstride_b;
    float* C = Cbase + (size_t)z * zstride_c;

    int tid = threadIdx.x;
    int w = tid >> 6, lane = tid & 63;
    int m0 = blockIdx.y * 64, n0 = blockIdx.x * 64;
    int wr = w >> 1, wc = w & 1;
    int fr = lane & 15, g8 = lane >> 4;

    int c = w * 64 + lane;
    int srow = c >> 2;
    int scol = (c & 3) ^ (srow & 3);
    unsigned lb = (unsigned)(w * 64) * 8;

    f4a z4 = {0.f, 0.f, 0.f, 0.f};
    f4a acc00 = z4, acc01 = z4, acc10 = z4, acc11 = z4;

    int ra0 = wr * 32 + fr, ra1 = ra0 + 16;
    int rb0 = wc * 32 + fr, rb1 = rb0 + 16;

#define STAGE(ph, k0)                                                         \
    {                                                                         \
        size_t ga = (size_t)(m0 + srow) * 512 + (k0) + scol * 8;              \
        size_t gb = (size_t)(n0 + srow) * 512 + (k0) + scol * 8;              \
        load_lds16(Ag_hi + ga, &lds[ph][0][lb]);                              \
        load_lds16(Ag_lo + ga, &lds[ph][1][lb]);                              \
        load_lds16(bhg + gb, &lds[ph][2][lb]);                                \
        load_lds16(blg + gb, &lds[ph][3][lb]);                                \
    }

#define FRAG(ph, buf, row) (*(const bf8*)&lds[ph][buf][(row) * 32 + (((g8) ^ ((row) & 3)) << 3)])

    STAGE(0, 0);
    __syncthreads();
    int ph = 0;
#pragma unroll 1
    for (int k0 = 0; k0 < 512; k0 += 32) {
        if (k0 + 32 < 512) STAGE(ph ^ 1, k0 + 32);
        bf8 fah0 = FRAG(ph, 0, ra0);
        bf8 fah1 = FRAG(ph, 0, ra1);
        bf8 fal0 = FRAG(ph, 1, ra0);
        bf8 fal1 = FRAG(ph, 1, ra1);
        bf8 fbh0 = FRAG(ph, 2, rb0);
        bf8 fbh1 = FRAG(ph, 2, rb1);
        bf8 fbl0 = FRAG(ph, 3, rb0);
        bf8 fbl1 = FRAG(ph, 3, rb1);
        acc00 = __builtin_amdgcn_mfma_f32_16x16x32_bf16(fah0, fbh0, acc00, 0, 0, 0);
        acc01 = __builtin_amdgcn_mfma_f32_16x16x32_bf16(fah0, fbh1, acc01, 0, 0, 0);
        acc10 = __builtin_amdgcn_mfma_f32_16x16x32_bf16(fah1, fbh0, acc10, 0, 0, 0);
        acc11 = __builtin_amdgcn_mfma_f32_16x16x32_bf16(fah1, fbh1, acc11, 0, 0, 0);
        acc00 = __builtin_amdgcn_mfma_f32_16x16x32_bf16(fah0, fbl0, acc00, 0, 0, 0);
        acc01 = __builtin_amdgcn_mfma_f32_16x16x32_bf16(fah0, fbl1, acc01, 0, 0, 0);
        acc10 = __builtin_amdgcn_mfma_f32_16x16x32_bf16(fah1, fbl0, acc10, 0, 0, 0);
        acc11 = __builtin_amdgcn_mfma_f32_16x16x32_bf16(fah1, fbl1, acc11, 0, 0, 0);
        acc00 = __builtin_amdgcn_mfma_f32_16x16x32_bf16(fal0, fbh0, acc00, 0, 0, 0);
        acc01 = __builtin_amdgcn_mfma_f32_16x16x32_bf16(fal0, fbh1, acc01, 0, 0, 0);
        acc10 = __builtin_amdgcn_mfma_f32_16x16x32_bf16(fal1, fbh0, acc10, 0, 0, 0);
        acc11 = __builtin_amdgcn_mfma_f32_16x16x32_bf16(fal1, fbh1, acc11, 0, 0, 0);
        __syncthreads();
        ph ^= 1;
    }
#undef STAGE
#undef FRAG

    int col0 = n0 + wc * 32 + fr, col1 = col0 + 16;
    int rbase0 = m0 + wr * 32 + g8 * 4;
    int rbase1 = rbase0 + 16;
    float b0 = bias ? bias[col0] : 0.f;
    float b1 = bias ? bias[col1] : 0.f;
#pragma unroll
    for (int r = 0; r < 4; ++r) {
        C[(size_t)(rbase0 + r) * 512 + col0] = acc00[r] + b0;
        C[(size_t)(rbase0 + r) * 512 + col1] = acc01[r] + b1;
        C[(size_t)(rbase1 + r) * 512 + col0] = acc10[r] + b0;
        C[(size_t)(rbase1 + r) * 512 + col1] = acc11[r] + b1;
    }
}

// ---------------------------------------------------------------------------
// Gate/complexity MLPs -> T_i. 2 tokens per 256-thread block, 1024 blocks.
// ---------------------------------------------------------------------------
__global__ __launch_bounds__(256) void mlp_gate_kernel(const float* __restrict__ x,
    const float* __restrict__ g1, const float* __restrict__ gb1,
    const float* __restrict__ g2, const float* __restrict__ gb2,
    const float* __restrict__ g3, const float* __restrict__ gb3,
    const float* __restrict__ c1, const float* __restrict__ cb1,
    const float* __restrict__ c2, const float* __restrict__ cb2,
    int* __restrict__ Ti)
{
    __shared__ __align__(16) float xsh[2][512];
    __shared__ float p1[2][4][64];
    __shared__ float h1sh[2][64];
    __shared__ float p2[2][4][32];
    __shared__ float gsh[2];
    int tid = threadIdx.x;
    int tok0 = blockIdx.x * 2;

    ((float4*)&xsh[0][0])[tid] = ((const float4*)&x[(size_t)tok0 * 512])[tid];
    __syncthreads();

    {
        int l = tid & 63, ec = tid >> 6;
        float a0 = 0.f, a1 = 0.f;
        int e0 = ec * 128;
#pragma unroll 8
        for (int t = 0; t < 128; ++t) {
            int e = e0 + t;
            float w = g1[e * 64 + l];
            a0 = fmaf(xsh[0][e], w, a0);
            a1 = fmaf(xsh[1][e], w, a1);
        }
        p1[0][ec][l] = a0;
        p1[1][ec][l] = a1;
    }
    __syncthreads();
    if (tid < 128) {
        int tok = tid >> 6, l = tid & 63;
        float h = p1[tok][0][l] + p1[tok][1][l] + p1[tok][2][l] + p1[tok][3][l] + gb1[l];
        h1sh[tok][l] = fmaxf(h, 0.f);
    }
    __syncthreads();
    {
        int m = tid & 31, g = tid >> 5, tok = g & 1, lc = g >> 1;
        float a = 0.f;
#pragma unroll
        for (int t = 0; t < 16; ++t) {
            int l = lc * 16 + t;
            a = fmaf(h1sh[tok][l], g2[l * 32 + m], a);
        }
        p2[tok][lc][m] = a;
    }
    __syncthreads();
    if (tid < 64) {
        int tok = tid >> 5, m = tid & 31;
        float h = p2[tok][0][m] + p2[tok][1][m] + p2[tok][2][m] + p2[tok][3][m] + gb2[m];
        h = fmaxf(h, 0.f);
        float v = h * g3[m];
#pragma unroll
        for (int o = 1; o < 32; o <<= 1) v += __shfl_xor(v, o);
        if (m == 0) gsh[tok] = 1.f / (1.f + expf(-(v + gb3[0])));
    }
    __syncthreads();
    {
        int m = tid & 31, g = tid >> 5, tok = g & 1, ec = g >> 1;
        float a = 0.f;
        int e0 = ec * 128;
#pragma unroll 8
        for (int t = 0; t < 128; ++t) {
            int e = e0 + t;
            a = fmaf(xsh[tok][e], c1[e * 32 + m], a);
        }
        p2[tok][ec][m] = a;
    }
    __syncthreads();
    if (tid < 64) {
        int tok = tid >> 5, m = tid & 31;
        float h = p2[tok][0][m] + p2[tok][1][m] + p2[tok][2][m] + p2[tok][3][m] + cb1[m];
        h = fmaxf(h, 0.f);
        float v = h * c2[m];
#pragma unroll
        for (int o = 1; o < 32; o <<= 1) v += __shfl_xor(v, o);
        if (m == 0) {
            float comp = 1.f / (1.f + expf(-(v + cb2[0])));
            float comb = 0.7f * gsh[tok] + 0.3f * comp;
            int t = (int)ceilf(comb * 20.f);
            t = t < 1 ? 1 : (t > 20 ? 20 : t);
            Ti[tok0 + tok] = t;
        }
    }
}

// ---------------------------------------------------------------------------
// LIF + window mask. One wave per (token, head). lane = channel within head.
// mode 0 (q): qpack[bh*512+i][t]  mode 1 (k): kpackT[bh][t][j]
// mode 2 (v): spike count as exact bf16 integer.
// ---------------------------------------------------------------------------
__global__ __launch_bounds__(256) void lif_kernel(const float* __restrict__ q,
    const float* __restrict__ k, const float* __restrict__ v,
    const int* __restrict__ Ti,
    const float* __restrict__ alphap, const float* __restrict__ betap,
    u64* __restrict__ qpack, u64* __restrict__ kpackT,
    unsigned short* __restrict__ vcnt_bf16)
{
    int mode = blockIdx.y;
    const float* src = (mode == 0) ? q : (mode == 1) ? k : v;
    int w = blockIdx.x * 4 + (threadIdx.x >> 6);   // 0..16383
    int lane = threadIdx.x & 63;
    int token = w >> 3;
    int h = w & 7;
    float xin = src[(size_t)token * 512 + h * 64 + lane];
    int T = Ti[token];
    float alpha = alphap[0], beta = betap[0];
    float vm = 0.f, isyn = 0.f;
    u64 myword = 0ull;
    int cnt = 0;
#pragma unroll
    for (int t = 0; t < TMAX; ++t) {
        isyn = alpha * isyn + xin;
        vm = beta * vm + isyn;
        bool sp = vm >= 1.0f;
        if (sp) vm = 0.f;
        bool msk = sp && (t < T);
        if (mode < 2) {
            u64 word = __ballot(msk ? 1 : 0);
            if (lane == t) myword = word;
        } else {
            cnt += msk ? 1 : 0;
        }
    }
    int b = token >> 9, i = token & 511;
    size_t bh = (size_t)(b * 8 + h);
    if (mode == 0) { if (lane < TMAX) qpack[(bh * 512 + i) * TMAX + lane] = myword; }
    else if (mode == 1) { if (lane < TMAX) kpackT[(bh * TMAX + lane) * 512 + i] = myword; }
    else { vcnt_bf16[(bh * 512 + i) * 64 + lane] = f2bf((float)cnt); }  // exact
}

// ---------------------------------------------------------------------------
// transpose vcnt: [bh][j][d] u16 -> vT[bh][d][j] u16. grid (8 jchunks, 32 bh).
// ---------------------------------------------------------------------------
__global__ __launch_bounds__(256) void vtrans_kernel(
    const unsigned short* __restrict__ vin, unsigned short* __restrict__ vout)
{
    __shared__ unsigned short t[64][80];   // pad 80: 16B-aligned rows
    int bh = blockIdx.y, j0 = blockIdx.x * 64;
    int tid = threadIdx.x;
    {
        int jl = tid >> 2, dc = (tid & 3) * 16;
        const unsigned short* src = vin + ((size_t)bh * 512 + j0 + jl) * 64 + dc;
        u16x8 a = *(const u16x8*)src;
        u16x8 b = *(const u16x8*)(src + 8);
#pragma unroll
        for (int k = 0; k < 8; ++k) t[dc + k][jl] = a[k];
#pragma unroll
        for (int k = 0; k < 8; ++k) t[dc + 8 + k][jl] = b[k];
    }
    __syncthreads();
    {
        int dl = tid >> 2, jc = (tid & 3) * 16;
        u16x8 o0 = *(const u16x8*)&t[dl][jc];
        u16x8 o1 = *(const u16x8*)&t[dl][jc + 8];
        unsigned short* dst = vout + ((size_t)bh * 64 + dl) * 512 + j0 + jc;
        *(u16x8*)dst = o0;
        *(u16x8*)(dst + 8) = o1;
    }
}

// ---------------------------------------------------------------------------
// attn: 256 threads (4 waves), 2048 blocks, LDS 18688 B -> 8 blocks/CU.
// (round-15 structure, known-good)
// ---------------------------------------------------------------------------
__global__ __launch_bounds__(256, 8) void attn_kernel(
    const u64* __restrict__ qpack,
    const u64* __restrict__ kpackT,
    const unsigned short* __restrict__ vT,
    const int* __restrict__ Ti,
    unsigned short* __restrict__ ctx_hi,
    unsigned short* __restrict__ ctx_lo)
{
    __shared__ __align__(16) float praw[4352];   // 17408 B (8 rows x 544 f32)
    __shared__ __align__(16) u64 qw[8][20];      // 1280 B q-word cache
    unsigned short* pb = (unsigned short*)praw;  // overlay: p_bf16 [16][520]

    int tid = threadIdx.x;
    int bid = blockIdx.x;
    int swz = (bid & 7) * 256 + (bid >> 3);      // XCD-bijective
    int bh = swz >> 6;                 // 0..31
    int i0 = (swz & 63) << 3;          // 8-row group
    int b = bh >> 3, h = bh & 7;

    // ---- maxT over the 8 q-rows (wave-uniform scalar loads; EXACT clamp) --
    int maxT = 1;
    {
        const int* tp = Ti + b * 512 + i0;
#pragma unroll
        for (int i = 0; i < 8; ++i) maxT = max(maxT, tp[i]);
    }

    // ---- Phase 0: stage q-words (160 contiguous u64) ----------------------
    {
        const u64* qsrc = qpack + ((size_t)bh * 512 + i0) * TMAX;
        if (tid < 160) ((u64*)qw)[tid] = qsrc[tid];
    }
    __syncthreads();

    // ---- Phase 1: scores; thread owns columns j = tid AND j+256 -----------
    {
        int j = tid;
        const u64* kc0 = kpackT + (size_t)bh * TMAX * 512 + j;
        const u64* kc1 = kc0 + 256;
        int acc0[8], acc1[8];
#pragma unroll
        for (int i = 0; i < 8; ++i) { acc0[i] = 0; acc1[i] = 0; }

#define SUPERPASS(T0)                                                          \
        {                                                                      \
            u64 ka[4], kb[4];                                                  \
            _Pragma("unroll")                                                  \
            for (int t = 0; t < 4; ++t) {                                      \
                ka[t] = kc0[(size_t)(T0 + t) * 512];                           \
                kb[t] = kc1[(size_t)(T0 + t) * 512];                           \
            }                                                                  \
            _Pragma("unroll")                                                  \
            for (int i = 0; i < 8; ++i) {                                      \
                ulonglong2 qa = *(const ulonglong2*)&qw[i][T0];                \
                ulonglong2 qb2 = *(const ulonglong2*)&qw[i][(T0) + 2];         \
                acc0[i] += __popcll(qa.x & ka[0]) + __popcll(qa.y & ka[1])     \
                         + __popcll(qb2.x & ka[2]) + __popcll(qb2.y & ka[3]);  \
                acc1[i] += __popcll(qa.x & kb[0]) + __popcll(qa.y & kb[1])     \
                         + __popcll(qb2.x & kb[2]) + __popcll(qb2.y & kb[3]);  \
            }                                                                  \
        }

        SUPERPASS(0)
        if (maxT > 4)  SUPERPASS(4)
        if (maxT > 8)  SUPERPASS(8)
        if (maxT > 12) SUPERPASS(12)
        if (maxT > 16) SUPERPASS(16)
#undef SUPERPASS

#pragma unroll
        for (int i = 0; i < 8; ++i) {
            praw[i * 544 + j]       = 0.125f * (float)acc0[i];
            praw[i * 544 + 256 + j] = 0.125f * (float)acc1[i];
        }
    }
    __syncthreads();

    // ---- Phase 2: softmax (8 rows x 32 lanes); p -> bf16 with 0.05/lsum ---
    {
        int row = tid >> 5, jc = tid & 31;
        float pv[16];
        float m = -1e30f;
#pragma unroll
        for (int s = 0; s < 16; ++s) {
            pv[s] = praw[row * 544 + jc + s * 32];
            m = fmaxf(m, pv[s]);
        }
#pragma unroll
        for (int o = 1; o < 32; o <<= 1) m = fmaxf(m, __shfl_xor(m, o));
        float lsum = 0.f;
#pragma unroll
        for (int s = 0; s < 16; ++s) {
            pv[s] = __expf(pv[s] - m);
            lsum += pv[s];
        }
#pragma unroll
        for (int o = 1; o < 32; o <<= 1) lsum += __shfl_xor(lsum, o);
        float inv = 0.05f / lsum;                  // includes the /TMAX of v_mean
        __syncthreads();   // ALL praw reads complete before pb overlay writes
#pragma unroll
        for (int s = 0; s < 16; ++s)
            pb[row * 520 + jc + s * 32] = f2bf(pv[s] * inv);
    }
    __syncthreads();

    // ---- Phase 3: PV via MFMA; wave w -> d-chunk [w*16, w*16+16) ----------
    {
        int wv = tid >> 6, lane = tid & 63;
        int d0 = wv * 16;
        const unsigned short* vrow =
            vT + ((size_t)bh * 64 + d0 + (lane & 15)) * 512 + (lane >> 4) * 8;
        const unsigned short* prow = pb + (lane & 15) * 520 + (lane >> 4) * 8;
        f4a acc = {0.f, 0.f, 0.f, 0.f};
#pragma unroll
        for (int ks = 0; ks < 16; ++ks) {
            bf8 af = *(const bf8*)(vrow + ks * 32);
            bf8 bf_ = *(const bf8*)(prow + ks * 32);
            acc = __builtin_amdgcn_mfma_f32_16x16x32_bf16(af, bf_, acc, 0, 0, 0);
        }
        // D: col = lane&15 = i (rows 0-7 valid), row = (lane>>4)*4+r = d
        int ic = lane & 15;
        if (ic < 8) {
            int dloc = d0 + (lane >> 4) * 4;
            ushort4 h4, l4;
            split1(acc[0], h4.x, l4.x);
            split1(acc[1], h4.y, l4.y);
            split1(acc[2], h4.z, l4.z);
            split1(acc[3], h4.w, l4.w);
            size_t off = ((size_t)(b * 512 + i0 + ic)) * 512 + h * 64 + dloc;
            *(ushort4*)&ctx_hi[off] = h4;
            *(ushort4*)&ctx_lo[off] = l4;
        }
    }
}

// ---------------------------------------------------------------------------
extern "C" void kernel_launch(void* const* d_in, const int* in_sizes, int n_in,
                              void* d_out, int out_size, void* d_ws, size_t ws_size,
                              hipStream_t stream) {
    const float* x   = (const float*)d_in[0];
    const float* Wq  = (const float*)d_in[1];
    const float* Wk  = (const float*)d_in[2];
    const float* Wv  = (const float*)d_in[3];
    const float* Wo  = (const float*)d_in[4];
    const float* bo  = (const float*)d_in[5];
    const float* g1  = (const float*)d_in[6];
    const float* gb1 = (const float*)d_in[7];
    const float* g2  = (const float*)d_in[8];
    const float* gb2 = (const float*)d_in[9];
    const float* g3  = (const float*)d_in[10];
    const float* gb3 = (const float*)d_in[11];
    const float* c1  = (const float*)d_in[12];
    const float* cb1 = (const float*)d_in[13];
    const float* c2  = (const float*)d_in[14];
    const float* cb2 = (const float*)d_in[15];
    const float* alpha = (const float*)d_in[16];
    const float* beta  = (const float*)d_in[17];
    float* out = (float*)d_out;

    char* w = (char*)d_ws;
    float* q    = (float*)w;                         w += (size_t)BS * E_ * 4;
    float* kbuf = (float*)w;                         w += (size_t)BS * E_ * 4;  // later ctx_hi/lo
    float* vbuf = (float*)w;                         w += (size_t)BS * E_ * 4;
    int* Ti     = (int*)w;                           w += (size_t)BS * 4;
    u64* qpack  = (u64*)w;                           w += (size_t)BS * NH * TMAX * 8;  // first: x_hi
    u64* kpackT = (u64*)w;                           w += (size_t)BS * NH * TMAX * 8;  // first: x_lo
    char* vregion = w;                               w += (size_t)BS * E_ * 4;  // wtqkv -> vcnt+vT
    unsigned short* wto_hi = (unsigned short*)w;     w += (size_t)512 * 512 * 2;
    unsigned short* wto_lo = (unsigned short*)w;     w += (size_t)512 * 512 * 2;

    unsigned short* x_hi = (unsigned short*)qpack;
    unsigned short* x_lo = (unsigned short*)kpackT;
    unsigned short* wtqkv_hi = (unsigned short*)vregion;               // 1.5 MB
    unsigned short* wtqkv_lo = (unsigned short*)vregion + (size_t)3 * 512 * 512;
    unsigned short* vcnt = (unsigned short*)vregion;                   // 2 MB (after gemm)
    unsigned short* vT   = (unsigned short*)vregion + (size_t)BS * E_; // 2 MB
    unsigned short* ctx_hi = (unsigned short*)kbuf;
    unsigned short* ctx_lo = (unsigned short*)kbuf + (size_t)BS * E_;

    // 1) fused: split x + transpose/split all W (one dispatch, 1280 blocks)
    split_all_kernel<<<1280, 256, 0, stream>>>(x, Wq, Wk, Wv, Wo,
        x_hi, x_lo, wtqkv_hi, wtqkv_lo, wto_hi, wto_lo);
    // 2) qkv projections (LDS-staged, 2-phase double-buffered)
    gemm_lds_kernel<<<dim3(8, 32, 3), 256, 0, stream>>>(x_hi, x_lo,
        wtqkv_hi, wtqkv_lo, q, nullptr, 512 * 512, BS * E_);
    // 3) windows
    mlp_gate_kernel<<<1024, 256, 0, stream>>>(x, g1, gb1, g2, gb2, g3, gb3,
                                              c1, cb1, c2, cb2, Ti);
    // 4) LIF (overwrites x_hi/lo and wtqkv regions - stream-ordered after gemm)
    lif_kernel<<<dim3(4096, 3), 256, 0, stream>>>(q, kbuf, vbuf, Ti, alpha, beta,
                                                  qpack, kpackT, vcnt);
    // 5) V transpose to [bh][d][j] bf16
    vtrans_kernel<<<dim3(8, 32), 256, 0, stream>>>(vcnt, vT);
    // 6) attention (emits ctx hi/lo bf16 directly)
    attn_kernel<<<2048, 256, 0, stream>>>(qpack, kpackT, vT, Ti, ctx_hi, ctx_lo);
    // 7) output projection (full K)
    gemm_lds_kernel<<<dim3(8, 32, 1), 256, 0, stream>>>(ctx_hi, ctx_lo,
        wto_hi, wto_lo, out, bo, 0, 0);
}